// Round 1
// baseline (1067.768 us; speedup 1.0000x reference)
//
#include <hip/hip_runtime.h>

#define D_FEAT 64

// One thread per float4 of edge_w: 16 threads cover one edge's 64-float row.
// Coalesced 16B/lane loads; 4 hardware fp32 global atomics per thread.
__global__ void spmm_scatter_add_kernel(const int* __restrict__ edge0,
                                        const float4* __restrict__ edge_w4,
                                        float* __restrict__ out,
                                        long long n_vec) {
    long long i = (long long)blockIdx.x * blockDim.x + threadIdx.x;
    if (i >= n_vec) return;
    long long e  = i >> 4;          // edge index (16 float4 per row)
    int      f4 = (int)(i & 15);    // which float4 within the row
    int idx = edge0[e];             // broadcast across 16 lanes, L1-served
    float4 v = edge_w4[i];
    float* dst = out + (long long)idx * D_FEAT + f4 * 4;
    unsafeAtomicAdd(dst + 0, v.x);
    unsafeAtomicAdd(dst + 1, v.y);
    unsafeAtomicAdd(dst + 2, v.z);
    unsafeAtomicAdd(dst + 3, v.w);
}

extern "C" void kernel_launch(void* const* d_in, const int* in_sizes, int n_in,
                              void* d_out, int out_size, void* d_ws, size_t ws_size,
                              hipStream_t stream) {
    const int*   edge   = (const int*)d_in[0];     // (2, E) row-major; edge[0] = first E
    const float* edge_w = (const float*)d_in[1];   // (E, 64) fp32
    float*       out    = (float*)d_out;           // (N, 64) fp32

    long long E = (long long)in_sizes[0] / 2;

    // Output must be zeroed every call (harness poisons once, never restores).
    hipMemsetAsync(d_out, 0, (size_t)out_size * sizeof(float), stream);

    long long n_vec = E * (D_FEAT / 4);            // E * 16 float4 elements
    int block = 256;
    long long grid = (n_vec + block - 1) / block;
    spmm_scatter_add_kernel<<<(unsigned)grid, block, 0, stream>>>(
        edge, (const float4*)edge_w, out, n_vec);
}

// Round 2
// 261.645 us; speedup vs baseline: 4.0810x; 4.0810x over previous
//
#include <hip/hip_runtime.h>

#define NFEAT 64
#define SCAN_BLOCK 1024

// ---------- fallback (R1 atomic kernel) in case ws is too small ----------
__global__ void spmm_scatter_add_kernel(const int* __restrict__ edge0,
                                        const float4* __restrict__ edge_w4,
                                        float* __restrict__ out,
                                        long long n_vec) {
    long long i = (long long)blockIdx.x * blockDim.x + threadIdx.x;
    if (i >= n_vec) return;
    long long e  = i >> 4;
    int      f4 = (int)(i & 15);
    int idx = edge0[e];
    float4 v = edge_w4[i];
    float* dst = out + (long long)idx * NFEAT + f4 * 4;
    unsafeAtomicAdd(dst + 0, v.x);
    unsafeAtomicAdd(dst + 1, v.y);
    unsafeAtomicAdd(dst + 2, v.z);
    unsafeAtomicAdd(dst + 3, v.w);
}

// ---------- CSR-build path ----------
__global__ void hist_kernel(const int* __restrict__ edge0, int* __restrict__ cnt, int E) {
    int e = blockIdx.x * blockDim.x + threadIdx.x;
    if (e < E) atomicAdd(&cnt[edge0[e]], 1);
}

// In-place exclusive scan over chunks of SCAN_BLOCK; per-block totals to bsums.
__global__ void scan_block_kernel(int* __restrict__ offs, int* __restrict__ bsums, int N) {
    __shared__ int sm[SCAN_BLOCK];
    int i = blockIdx.x * SCAN_BLOCK + threadIdx.x;
    int v = (i < N) ? offs[i] : 0;
    sm[threadIdx.x] = v;
    __syncthreads();
    for (int d = 1; d < SCAN_BLOCK; d <<= 1) {
        int t = (threadIdx.x >= d) ? sm[threadIdx.x - d] : 0;
        __syncthreads();
        sm[threadIdx.x] += t;
        __syncthreads();
    }
    if (i < N) offs[i] = sm[threadIdx.x] - v;              // exclusive
    if (threadIdx.x == SCAN_BLOCK - 1) bsums[blockIdx.x] = sm[SCAN_BLOCK - 1];
}

__global__ void scan_sums_kernel(int* bsums, int nb) {
    if (threadIdx.x == 0 && blockIdx.x == 0) {
        int acc = 0;
        for (int b = 0; b < nb; ++b) { int v = bsums[b]; bsums[b] = acc; acc += v; }
    }
}

__global__ void scan_finalize_kernel(int* __restrict__ offs, int* __restrict__ cur,
                                     const int* __restrict__ bsums, int N, int E) {
    int i = blockIdx.x * SCAN_BLOCK + threadIdx.x;
    if (i < N) {
        int o = offs[i] + bsums[blockIdx.x];
        offs[i] = o;
        cur[i]  = o;
    }
    if (i == 0) offs[N] = E;
}

__global__ void scatter_kernel(const int* __restrict__ edge0, int* __restrict__ cur,
                               int* __restrict__ bucket, int E) {
    int e = blockIdx.x * blockDim.x + threadIdx.x;
    if (e < E) {
        int idx = edge0[e];
        int pos = atomicAdd(&cur[idx], 1);
        bucket[pos] = e;
    }
}

// One wave per node; lane = feature. 256B coalesced row reads, unroll 4 for MLP.
__global__ void gather_kernel(const int* __restrict__ offs, const int* __restrict__ bucket,
                              const float* __restrict__ w, float* __restrict__ out, int N) {
    int n = blockIdx.x * 4 + threadIdx.y;
    if (n >= N) return;
    int lane = threadIdx.x;
    int s = offs[n], t = offs[n + 1];
    float a0 = 0.f, a1 = 0.f, a2 = 0.f, a3 = 0.f;
    int e = s;
    for (; e + 4 <= t; e += 4) {
        int e0 = bucket[e], e1 = bucket[e + 1], e2 = bucket[e + 2], e3 = bucket[e + 3];
        a0 += w[(long long)e0 * NFEAT + lane];
        a1 += w[(long long)e1 * NFEAT + lane];
        a2 += w[(long long)e2 * NFEAT + lane];
        a3 += w[(long long)e3 * NFEAT + lane];
    }
    for (; e < t; ++e) a0 += w[(long long)bucket[e] * NFEAT + lane];
    out[(long long)n * NFEAT + lane] = (a0 + a1) + (a2 + a3);
}

extern "C" void kernel_launch(void* const* d_in, const int* in_sizes, int n_in,
                              void* d_out, int out_size, void* d_ws, size_t ws_size,
                              hipStream_t stream) {
    const int*   edge   = (const int*)d_in[0];     // (2, E): edge[0] = first E entries
    const float* edge_w = (const float*)d_in[1];   // (E, 64) fp32
    float*       out    = (float*)d_out;           // (N, 64) fp32

    int E = in_sizes[0] / 2;
    int N = out_size / NFEAT;
    int nb = (N + SCAN_BLOCK - 1) / SCAN_BLOCK;

    size_t need = ((size_t)(N + 1) + (size_t)N + (size_t)nb + (size_t)E) * sizeof(int);
    if (ws_size < need) {
        // fallback: direct fp32 atomics (R1 path)
        hipMemsetAsync(d_out, 0, (size_t)out_size * sizeof(float), stream);
        long long n_vec = (long long)E * (NFEAT / 4);
        spmm_scatter_add_kernel<<<(unsigned)((n_vec + 255) / 256), 256, 0, stream>>>(
            edge, (const float4*)edge_w, out, n_vec);
        return;
    }

    int* offs   = (int*)d_ws;          // N+1 (doubles as counts before scan)
    int* cur    = offs + (N + 1);      // N
    int* bsums  = cur + N;             // nb
    int* bucket = bsums + nb;          // E

    // 1. zero counts
    hipMemsetAsync(offs, 0, (size_t)(N + 1) * sizeof(int), stream);
    // 2. histogram
    hist_kernel<<<(E + 255) / 256, 256, 0, stream>>>(edge, offs, E);
    // 3. exclusive scan (in place) -> offs, cur
    scan_block_kernel<<<nb, SCAN_BLOCK, 0, stream>>>(offs, bsums, N);
    scan_sums_kernel<<<1, 64, 0, stream>>>(bsums, nb);
    scan_finalize_kernel<<<nb, SCAN_BLOCK, 0, stream>>>(offs, cur, bsums, N, E);
    // 4. scatter edge ids into buckets
    scatter_kernel<<<(E + 255) / 256, 256, 0, stream>>>(edge, cur, bucket, E);
    // 5. gather-sum: one wave per node
    dim3 gblock(64, 4);
    gather_kernel<<<(N + 3) / 4, gblock, 0, stream>>>(offs, bucket, edge_w, out, N);
}

// Round 3
// 238.071 us; speedup vs baseline: 4.4851x; 1.0990x over previous
//
#include <hip/hip_runtime.h>

#define NFEAT 64
#define SCAN_BLOCK 1024

// ---------- CSR build ----------
__global__ void hist_kernel(const int* __restrict__ edge0, int* __restrict__ cnt, int E) {
    int e = blockIdx.x * blockDim.x + threadIdx.x;
    if (e < E) atomicAdd(&cnt[edge0[e]], 1);
}

// In-place exclusive scan over chunks of SCAN_BLOCK; per-block totals to bsums.
__global__ void scan_block_kernel(int* __restrict__ offs, int* __restrict__ bsums, int N) {
    __shared__ int sm[SCAN_BLOCK];
    int i = blockIdx.x * SCAN_BLOCK + threadIdx.x;
    int v = (i < N) ? offs[i] : 0;
    sm[threadIdx.x] = v;
    __syncthreads();
    for (int d = 1; d < SCAN_BLOCK; d <<= 1) {
        int t = (threadIdx.x >= d) ? sm[threadIdx.x - d] : 0;
        __syncthreads();
        sm[threadIdx.x] += t;
        __syncthreads();
    }
    if (i < N) offs[i] = sm[threadIdx.x] - v;              // exclusive
    if (threadIdx.x == SCAN_BLOCK - 1) bsums[blockIdx.x] = sm[SCAN_BLOCK - 1];
}

// Wave-parallel exclusive scan of the (small) block-sums array. 1 block x 64.
__global__ void scan_sums_kernel(int* __restrict__ bsums, int nb) {
    int lane = threadIdx.x;
    int carry = 0;
    for (int base = 0; base < nb; base += 64) {
        int i = base + lane;
        int orig = (i < nb) ? bsums[i] : 0;
        int v = orig;
        #pragma unroll
        for (int d = 1; d < 64; d <<= 1) {
            int t = __shfl_up(v, d);
            if (lane >= d) v += t;
        }
        if (i < nb) bsums[i] = carry + v - orig;           // exclusive
        carry += __shfl(v, 63);
    }
}

__global__ void scan_finalize_kernel(int* __restrict__ offs, int* __restrict__ cur,
                                     const int* __restrict__ bsums, int N, int E) {
    int i = blockIdx.x * SCAN_BLOCK + threadIdx.x;
    if (i < N) {
        int o = offs[i] + bsums[blockIdx.x];
        offs[i] = o;
        cur[i]  = o;
    }
    if (i == 0) offs[N] = E;
}

__global__ void scatter_kernel(const int* __restrict__ edge0, int* __restrict__ cur,
                               int* __restrict__ bucket, int E) {
    int e = blockIdx.x * blockDim.x + threadIdx.x;
    if (e < E) {
        int idx = edge0[e];
        int pos = atomicAdd(&cur[idx], 1);
        bucket[pos] = e;
    }
}

// One wave per node. lane = (g = lane>>4 edge-subgroup, fq = lane&15 float4 slot).
// Each global_load_dwordx4 moves 4 full edge rows (1 KB) per wave; unroll x2.
// Cross-group reduce via 2 rounds of shfl_xor(16,32); lanes 0..15 write the row.
__global__ void gather_kernel(const int* __restrict__ offs, const int* __restrict__ bucket,
                              const float4* __restrict__ w4, float4* __restrict__ out4, int N) {
    int n = blockIdx.x * blockDim.y + threadIdx.y;
    if (n >= N) return;
    int lane = threadIdx.x;
    int g  = lane >> 4;     // 0..3: which edge within a 4-edge step
    int fq = lane & 15;     // 0..15: which float4 of the 64-float row
    int s = offs[n], t = offs[n + 1];

    float4 a0 = {0.f, 0.f, 0.f, 0.f};
    float4 a1 = {0.f, 0.f, 0.f, 0.f};
    int e = s;
    for (; e + 7 < t; e += 8) {
        int r0 = bucket[e + g];
        int r1 = bucket[e + 4 + g];
        float4 v0 = w4[(long long)r0 * 16 + fq];
        float4 v1 = w4[(long long)r1 * 16 + fq];
        a0.x += v0.x; a0.y += v0.y; a0.z += v0.z; a0.w += v0.w;
        a1.x += v1.x; a1.y += v1.y; a1.z += v1.z; a1.w += v1.w;
    }
    if (e + g < t) {
        int r = bucket[e + g];
        float4 v = w4[(long long)r * 16 + fq];
        a0.x += v.x; a0.y += v.y; a0.z += v.z; a0.w += v.w;
    }
    if (e + 4 + g < t) {
        int r = bucket[e + 4 + g];
        float4 v = w4[(long long)r * 16 + fq];
        a1.x += v.x; a1.y += v.y; a1.z += v.z; a1.w += v.w;
    }
    a0.x += a1.x; a0.y += a1.y; a0.z += a1.z; a0.w += a1.w;
    #pragma unroll
    for (int m = 16; m <= 32; m <<= 1) {
        a0.x += __shfl_xor(a0.x, m);
        a0.y += __shfl_xor(a0.y, m);
        a0.z += __shfl_xor(a0.z, m);
        a0.w += __shfl_xor(a0.w, m);
    }
    if (g == 0) out4[(long long)n * 16 + fq] = a0;
}

extern "C" void kernel_launch(void* const* d_in, const int* in_sizes, int n_in,
                              void* d_out, int out_size, void* d_ws, size_t ws_size,
                              hipStream_t stream) {
    const int*   edge   = (const int*)d_in[0];     // (2, E): edge[0] = first E entries
    const float* edge_w = (const float*)d_in[1];   // (E, 64) fp32
    float*       out    = (float*)d_out;           // (N, 64) fp32

    int E = in_sizes[0] / 2;
    int N = out_size / NFEAT;
    int nb = (N + SCAN_BLOCK - 1) / SCAN_BLOCK;

    int* offs   = (int*)d_ws;          // N+1 (counts before scan, then row offsets)
    int* cur    = offs + (N + 1);      // N   (running fill cursor)
    int* bsums  = cur + N;             // nb
    int* bucket = bsums + nb;          // E   (edge ids grouped by node)

    hipMemsetAsync(offs, 0, (size_t)(N + 1) * sizeof(int), stream);
    hist_kernel<<<(E + 255) / 256, 256, 0, stream>>>(edge, offs, E);
    scan_block_kernel<<<nb, SCAN_BLOCK, 0, stream>>>(offs, bsums, N);
    scan_sums_kernel<<<1, 64, 0, stream>>>(bsums, nb);
    scan_finalize_kernel<<<nb, SCAN_BLOCK, 0, stream>>>(offs, cur, bsums, N, E);
    scatter_kernel<<<(E + 255) / 256, 256, 0, stream>>>(edge, cur, bucket, E);

    dim3 gblock(64, 4);
    gather_kernel<<<(N + 3) / 4, gblock, 0, stream>>>(
        offs, bucket, (const float4*)edge_w, (float4*)out, N);
}

// Round 4
// 156.368 us; speedup vs baseline: 6.8286x; 1.5225x over previous
//
#include <hip/hip_runtime.h>

#define NFEAT 64
#define SCAN_BLOCK 1024

typedef __attribute__((ext_vector_type(4))) float f4vec;

__device__ inline f4vec ntload(const f4vec* p) { return __builtin_nontemporal_load(p); }

// ---------- fallback (direct fp32 atomics) if ws is too small ----------
__global__ void spmm_scatter_add_kernel(const int* __restrict__ edge0,
                                        const float4* __restrict__ edge_w4,
                                        float* __restrict__ out,
                                        long long n_vec) {
    long long i = (long long)blockIdx.x * blockDim.x + threadIdx.x;
    if (i >= n_vec) return;
    long long e  = i >> 4;
    int      f4 = (int)(i & 15);
    int idx = edge0[e];
    float4 v = edge_w4[i];
    float* dst = out + (long long)idx * NFEAT + f4 * 4;
    unsafeAtomicAdd(dst + 0, v.x);
    unsafeAtomicAdd(dst + 1, v.y);
    unsafeAtomicAdd(dst + 2, v.z);
    unsafeAtomicAdd(dst + 3, v.w);
}

// ---------- CSR build ----------
// Histogram AND per-edge rank in one pass: rank[e] = old count.
__global__ void hist_rank_kernel(const int* __restrict__ edge0, int* __restrict__ cnt,
                                 int* __restrict__ rank, int E) {
    int e = blockIdx.x * blockDim.x + threadIdx.x;
    if (e < E) rank[e] = atomicAdd(&cnt[edge0[e]], 1);
}

// In-place exclusive scan over chunks of SCAN_BLOCK; per-block totals to bsums.
__global__ void scan_block_kernel(int* __restrict__ offs, int* __restrict__ bsums, int N) {
    __shared__ int sm[SCAN_BLOCK];
    int i = blockIdx.x * SCAN_BLOCK + threadIdx.x;
    int v = (i < N) ? offs[i] : 0;
    sm[threadIdx.x] = v;
    __syncthreads();
    for (int d = 1; d < SCAN_BLOCK; d <<= 1) {
        int t = (threadIdx.x >= d) ? sm[threadIdx.x - d] : 0;
        __syncthreads();
        sm[threadIdx.x] += t;
        __syncthreads();
    }
    if (i < N) offs[i] = sm[threadIdx.x] - v;              // exclusive
    if (threadIdx.x == SCAN_BLOCK - 1) bsums[blockIdx.x] = sm[SCAN_BLOCK - 1];
}

// Each block redundantly reduces bsums[0..blockIdx) with one wave (nb is tiny),
// then adds the prefix to its chunk. Folds the old scan_sums launch away.
__global__ void scan_finalize_kernel(int* __restrict__ offs, const int* __restrict__ bsums,
                                     int nb, int N, int E) {
    __shared__ int prefix_sm;
    if (threadIdx.x < 64) {
        int lane = threadIdx.x;
        int acc = 0;
        for (int j = lane; j < nb; j += 64)
            if (j < (int)blockIdx.x) acc += bsums[j];
        #pragma unroll
        for (int m = 1; m < 64; m <<= 1) acc += __shfl_xor(acc, m);
        if (lane == 0) prefix_sm = acc;
    }
    __syncthreads();
    int i = blockIdx.x * SCAN_BLOCK + threadIdx.x;
    if (i < N) offs[i] += prefix_sm;
    if (i == 0) offs[N] = E;
}

// Atomic-free scatter: pure streaming reads + one 4B scattered write.
__global__ void scatter_nr_kernel(const int* __restrict__ edge0, const int* __restrict__ offs,
                                  const int* __restrict__ rank, int* __restrict__ bucket, int E) {
    int e = blockIdx.x * blockDim.x + threadIdx.x;
    if (e < E) bucket[offs[edge0[e]] + rank[e]] = e;
}

// One wave per node. g = lane>>4 (edge sub-slot), fq = lane&15 (float4 slot).
// Nontemporal row loads: edge_w is read-once, keep it out of L2.
__global__ __launch_bounds__(256, 8)
void gather_kernel(const int* __restrict__ offs, const int* __restrict__ bucket,
                   const f4vec* __restrict__ w4, f4vec* __restrict__ out4, int N) {
    int n = blockIdx.x * blockDim.y + threadIdx.y;
    if (n >= N) return;
    int lane = threadIdx.x;
    int g  = lane >> 4;
    int fq = lane & 15;
    int s = offs[n], t = offs[n + 1];

    f4vec a0 = {0.f, 0.f, 0.f, 0.f};
    f4vec a1 = {0.f, 0.f, 0.f, 0.f};
    int e = s;
    for (; e + 8 <= t; e += 8) {
        int r0 = bucket[e + g];
        int r1 = bucket[e + 4 + g];
        f4vec v0 = ntload(w4 + (long long)r0 * 16 + fq);
        f4vec v1 = ntload(w4 + (long long)r1 * 16 + fq);
        a0 += v0;
        a1 += v1;
    }
    if (e + g < t)     a0 += ntload(w4 + (long long)bucket[e + g] * 16 + fq);
    if (e + 4 + g < t) a1 += ntload(w4 + (long long)bucket[e + 4 + g] * 16 + fq);
    a0 += a1;
    #pragma unroll
    for (int m = 16; m <= 32; m <<= 1) {
        a0.x += __shfl_xor(a0.x, m);
        a0.y += __shfl_xor(a0.y, m);
        a0.z += __shfl_xor(a0.z, m);
        a0.w += __shfl_xor(a0.w, m);
    }
    if (g == 0) __builtin_nontemporal_store(a0, out4 + (long long)n * 16 + fq);
}

extern "C" void kernel_launch(void* const* d_in, const int* in_sizes, int n_in,
                              void* d_out, int out_size, void* d_ws, size_t ws_size,
                              hipStream_t stream) {
    const int*   edge   = (const int*)d_in[0];     // (2, E): edge[0] = first E entries
    const float* edge_w = (const float*)d_in[1];   // (E, 64) fp32
    float*       out    = (float*)d_out;           // (N, 64) fp32

    int E = in_sizes[0] / 2;
    int N = out_size / NFEAT;
    int nb = (N + SCAN_BLOCK - 1) / SCAN_BLOCK;

    size_t need = ((size_t)(N + 1) + (size_t)nb + 2ull * (size_t)E) * sizeof(int);
    if (ws_size < need) {
        hipMemsetAsync(d_out, 0, (size_t)out_size * sizeof(float), stream);
        long long n_vec = (long long)E * (NFEAT / 4);
        spmm_scatter_add_kernel<<<(unsigned)((n_vec + 255) / 256), 256, 0, stream>>>(
            edge, (const float4*)edge_w, out, n_vec);
        return;
    }

    int* offs   = (int*)d_ws;          // N+1 (counts before scan, then row offsets)
    int* bsums  = offs + (N + 1);      // nb
    int* rank   = bsums + nb;          // E
    int* bucket = rank + E;            // E

    hipMemsetAsync(offs, 0, (size_t)(N + 1) * sizeof(int), stream);
    hist_rank_kernel<<<(E + 255) / 256, 256, 0, stream>>>(edge, offs, rank, E);
    scan_block_kernel<<<nb, SCAN_BLOCK, 0, stream>>>(offs, bsums, N);
    scan_finalize_kernel<<<nb, SCAN_BLOCK, 0, stream>>>(offs, bsums, nb, N, E);
    scatter_nr_kernel<<<(E + 255) / 256, 256, 0, stream>>>(edge, offs, rank, bucket, E);

    dim3 gblock(64, 4);
    gather_kernel<<<(N + 3) / 4, gblock, 0, stream>>>(
        offs, bucket, (const f4vec*)edge_w, (f4vec*)out, N);
}

// Round 5
// 155.840 us; speedup vs baseline: 6.8517x; 1.0034x over previous
//
#include <hip/hip_runtime.h>

#define NFEAT 64
#define SCAN_BLOCK 1024

typedef __attribute__((ext_vector_type(4))) float f4vec;

__device__ inline f4vec ntload(const f4vec* p) { return __builtin_nontemporal_load(p); }

// ---------- fallback (direct fp32 atomics) if ws is too small ----------
__global__ void spmm_scatter_add_kernel(const int* __restrict__ edge0,
                                        const float4* __restrict__ edge_w4,
                                        float* __restrict__ out,
                                        long long n_vec) {
    long long i = (long long)blockIdx.x * blockDim.x + threadIdx.x;
    if (i >= n_vec) return;
    long long e  = i >> 4;
    int      f4 = (int)(i & 15);
    int idx = edge0[e];
    float4 v = edge_w4[i];
    float* dst = out + (long long)idx * NFEAT + f4 * 4;
    unsafeAtomicAdd(dst + 0, v.x);
    unsafeAtomicAdd(dst + 1, v.y);
    unsafeAtomicAdd(dst + 2, v.z);
    unsafeAtomicAdd(dst + 3, v.w);
}

// ---------- CSR build ----------
// Histogram + per-edge rank (old count) in one pass. 4 edges/thread.
__global__ void hist_rank_kernel(const int4* __restrict__ edge4, int* __restrict__ cnt,
                                 ushort* __restrict__ rank, int E4) {
    int i = blockIdx.x * blockDim.x + threadIdx.x;
    if (i >= E4) return;
    int4 idx = edge4[i];
    int e = i * 4;
    rank[e + 0] = (ushort)atomicAdd(&cnt[idx.x], 1);
    rank[e + 1] = (ushort)atomicAdd(&cnt[idx.y], 1);
    rank[e + 2] = (ushort)atomicAdd(&cnt[idx.z], 1);
    rank[e + 3] = (ushort)atomicAdd(&cnt[idx.w], 1);
}

// In-place exclusive scan over chunks of SCAN_BLOCK; per-block totals to bsums.
__global__ void scan_block_kernel(int* __restrict__ offs, int* __restrict__ bsums, int N) {
    __shared__ int sm[SCAN_BLOCK];
    int i = blockIdx.x * SCAN_BLOCK + threadIdx.x;
    int v = (i < N) ? offs[i] : 0;
    sm[threadIdx.x] = v;
    __syncthreads();
    for (int d = 1; d < SCAN_BLOCK; d <<= 1) {
        int t = (threadIdx.x >= d) ? sm[threadIdx.x - d] : 0;
        __syncthreads();
        sm[threadIdx.x] += t;
        __syncthreads();
    }
    if (i < N) offs[i] = sm[threadIdx.x] - v;              // exclusive
    if (threadIdx.x == SCAN_BLOCK - 1) bsums[blockIdx.x] = sm[SCAN_BLOCK - 1];
}

// Each block redundantly reduces bsums[0..blockIdx) with one wave (nb tiny).
__global__ void scan_finalize_kernel(int* __restrict__ offs, const int* __restrict__ bsums,
                                     int nb, int N, int E) {
    __shared__ int prefix_sm;
    if (threadIdx.x < 64) {
        int lane = threadIdx.x;
        int acc = 0;
        for (int j = lane; j < nb; j += 64)
            if (j < (int)blockIdx.x) acc += bsums[j];
        #pragma unroll
        for (int m = 1; m < 64; m <<= 1) acc += __shfl_xor(acc, m);
        if (lane == 0) prefix_sm = acc;
    }
    __syncthreads();
    int i = blockIdx.x * SCAN_BLOCK + threadIdx.x;
    if (i < N) offs[i] += prefix_sm;
    if (i == 0) offs[N] = E;
}

// Atomic-free scatter: streaming reads, offs L2-hit, one 4B scattered write/edge.
__global__ void scatter_nr_kernel(const int4* __restrict__ edge4, const int* __restrict__ offs,
                                  const ushort* __restrict__ rank, int* __restrict__ bucket, int E4) {
    int i = blockIdx.x * blockDim.x + threadIdx.x;
    if (i >= E4) return;
    int4 idx = edge4[i];
    int e = i * 4;
    ushort4 rk = *(const ushort4*)(rank + e);
    bucket[offs[idx.x] + rk.x] = e + 0;
    bucket[offs[idx.y] + rk.y] = e + 1;
    bucket[offs[idx.z] + rk.z] = e + 2;
    bucket[offs[idx.w] + rk.w] = e + 3;
}

// One wave per node. g = lane>>4 (edge sub-slot), fq = lane&15 (float4 slot).
// Main loop: 16 edges (4 KB) in flight per wave; then 8-step; then masked tail.
__global__ __launch_bounds__(256, 8)
void gather_kernel(const int* __restrict__ offs, const int* __restrict__ bucket,
                   const f4vec* __restrict__ w4, f4vec* __restrict__ out4, int N) {
    int n = blockIdx.x * blockDim.y + threadIdx.y;
    if (n >= N) return;
    int lane = threadIdx.x;
    int g  = lane >> 4;
    int fq = lane & 15;
    int s = offs[n], t = offs[n + 1];

    f4vec a0 = {0.f, 0.f, 0.f, 0.f};
    f4vec a1 = {0.f, 0.f, 0.f, 0.f};
    f4vec a2 = {0.f, 0.f, 0.f, 0.f};
    f4vec a3 = {0.f, 0.f, 0.f, 0.f};
    int e = s;
    for (; e + 16 <= t; e += 16) {
        int r0 = bucket[e + g];
        int r1 = bucket[e + 4 + g];
        int r2 = bucket[e + 8 + g];
        int r3 = bucket[e + 12 + g];
        a0 += ntload(w4 + (long long)r0 * 16 + fq);
        a1 += ntload(w4 + (long long)r1 * 16 + fq);
        a2 += ntload(w4 + (long long)r2 * 16 + fq);
        a3 += ntload(w4 + (long long)r3 * 16 + fq);
    }
    if (e + 8 <= t) {
        int r0 = bucket[e + g];
        int r1 = bucket[e + 4 + g];
        a0 += ntload(w4 + (long long)r0 * 16 + fq);
        a1 += ntload(w4 + (long long)r1 * 16 + fq);
        e += 8;
    }
    if (e + g < t)     a2 += ntload(w4 + (long long)bucket[e + g] * 16 + fq);
    if (e + 4 + g < t) a3 += ntload(w4 + (long long)bucket[e + 4 + g] * 16 + fq);
    a0 += a1;
    a2 += a3;
    a0 += a2;
    #pragma unroll
    for (int m = 16; m <= 32; m <<= 1) {
        a0.x += __shfl_xor(a0.x, m);
        a0.y += __shfl_xor(a0.y, m);
        a0.z += __shfl_xor(a0.z, m);
        a0.w += __shfl_xor(a0.w, m);
    }
    if (g == 0) __builtin_nontemporal_store(a0, out4 + (long long)n * 16 + fq);
}

extern "C" void kernel_launch(void* const* d_in, const int* in_sizes, int n_in,
                              void* d_out, int out_size, void* d_ws, size_t ws_size,
                              hipStream_t stream) {
    const int*   edge   = (const int*)d_in[0];     // (2, E): edge[0] = first E entries
    const float* edge_w = (const float*)d_in[1];   // (E, 64) fp32
    float*       out    = (float*)d_out;           // (N, 64) fp32

    int E = in_sizes[0] / 2;
    int N = out_size / NFEAT;
    int nb = (N + SCAN_BLOCK - 1) / SCAN_BLOCK;

    // ushort rank (aligned to 4B), int bucket, int offs/bsums
    size_t need = ((size_t)(N + 1) + (size_t)nb + (size_t)E) * sizeof(int)
                + (size_t)E * sizeof(ushort) + 64;
    bool vec_ok = (E % 4 == 0);
    if (ws_size < need || !vec_ok) {
        hipMemsetAsync(d_out, 0, (size_t)out_size * sizeof(float), stream);
        long long n_vec = (long long)E * (NFEAT / 4);
        spmm_scatter_add_kernel<<<(unsigned)((n_vec + 255) / 256), 256, 0, stream>>>(
            edge, (const float4*)edge_w, out, n_vec);
        return;
    }

    int*    offs   = (int*)d_ws;           // N+1 (counts before scan, then row offsets)
    int*    bsums  = offs + (N + 1);       // nb
    int*    bucket = bsums + nb;           // E
    ushort* rank   = (ushort*)(bucket + E);// E (2B each)

    int E4 = E / 4;
    hipMemsetAsync(offs, 0, (size_t)(N + 1) * sizeof(int), stream);
    hist_rank_kernel<<<(E4 + 255) / 256, 256, 0, stream>>>((const int4*)edge, offs, rank, E4);
    scan_block_kernel<<<nb, SCAN_BLOCK, 0, stream>>>(offs, bsums, N);
    scan_finalize_kernel<<<nb, SCAN_BLOCK, 0, stream>>>(offs, bsums, nb, N, E);
    scatter_nr_kernel<<<(E4 + 255) / 256, 256, 0, stream>>>((const int4*)edge, offs, rank, bucket, E4);

    dim3 gblock(64, 4);
    gather_kernel<<<(N + 3) / 4, gblock, 0, stream>>>(
        offs, bucket, (const f4vec*)edge_w, (f4vec*)out, N);
}

// Round 6
// 138.306 us; speedup vs baseline: 7.7203x; 1.1268x over previous
//
#include <hip/hip_runtime.h>

#define NFEAT 64
#define SCAN_BLOCK 1024
#define HIST_B 128           // edge chunks / hist blocks
#define HIST_T 512           // threads per hist block
#define NODE_HALF 25024      // nodes per LDS half-pass (covers N=50000 in 2 passes)

typedef __attribute__((ext_vector_type(4))) float f4vec;

__device__ inline f4vec ntload(const f4vec* p) { return __builtin_nontemporal_load(p); }

// ---------- fallback (direct fp32 atomics) if ws too small / odd shapes ----------
__global__ void spmm_scatter_add_kernel(const int* __restrict__ edge0,
                                        const float4* __restrict__ edge_w4,
                                        float* __restrict__ out,
                                        long long n_vec) {
    long long i = (long long)blockIdx.x * blockDim.x + threadIdx.x;
    if (i >= n_vec) return;
    long long e  = i >> 4;
    int      f4 = (int)(i & 15);
    int idx = edge0[e];
    float4 v = edge_w4[i];
    float* dst = out + (long long)idx * NFEAT + f4 * 4;
    unsafeAtomicAdd(dst + 0, v.x);
    unsafeAtomicAdd(dst + 1, v.y);
    unsafeAtomicAdd(dst + 2, v.z);
    unsafeAtomicAdd(dst + 3, v.w);
}

// ---------- CSR build, atomic-free (LDS histogram) ----------
// Block b owns edges [b*chunk, b*chunk+chunk). Two half-passes over node space
// with a packed 2xushort-per-uint LDS histogram (50KB). Outputs:
//   part[b][n]  = count of node n within chunk b  (later: column prefix)
//   lrank[e]    = rank of edge e within (chunk b, node n)
__global__ __launch_bounds__(HIST_T)
void hist_lds_kernel(const int* __restrict__ edge0, ushort* __restrict__ part,
                     ushort* __restrict__ lrank, int E, int chunk, int N) {
    __shared__ unsigned int lh[NODE_HALF / 2];    // 12512 uints = 50KB
    int b = blockIdx.x;
    int e0 = b * chunk;
    int e1 = min(e0 + chunk, E);
    for (int h = 0; h < 2; ++h) {
        int lo = h * NODE_HALF;
        int hi = min(lo + NODE_HALF, N);
        for (int i = threadIdx.x; i < NODE_HALF / 2; i += HIST_T) lh[i] = 0;
        __syncthreads();
        for (int e = e0 + threadIdx.x; e < e1; e += HIST_T) {
            int n = edge0[e];
            if (n >= lo && n < hi) {
                int l = n - lo;
                unsigned int inc = (l & 1) ? 0x10000u : 1u;
                unsigned int old = atomicAdd(&lh[l >> 1], inc);
                lrank[e] = (ushort)((l & 1) ? (old >> 16) : (old & 0xFFFFu));
            }
        }
        __syncthreads();
        if (lo < N) {
            unsigned int* dst = (unsigned int*)(part + (size_t)b * N + lo);
            int words = (hi - lo) >> 1;   // N even
            for (int i = threadIdx.x; i < words; i += HIST_T) dst[i] = lh[i];
        }
        __syncthreads();
    }
}

// Column-exclusive-scan part[*][n] in place (run <= degree, fits ushort), then
// block-level exclusive scan of the per-node totals -> offs chunk + bsums.
__global__ void scan_block_kernel(ushort* __restrict__ part, int* __restrict__ offs,
                                  int* __restrict__ bsums, int N, int B) {
    __shared__ int sm[SCAN_BLOCK];
    int i = blockIdx.x * SCAN_BLOCK + threadIdx.x;
    int run = 0;
    if (i < N) {
        #pragma unroll 8
        for (int b = 0; b < B; ++b) {
            size_t idx = (size_t)b * N + i;
            int c = part[idx];
            part[idx] = (ushort)run;
            run += c;
        }
    }
    int v = run;
    sm[threadIdx.x] = v;
    __syncthreads();
    for (int d = 1; d < SCAN_BLOCK; d <<= 1) {
        int t = (threadIdx.x >= d) ? sm[threadIdx.x - d] : 0;
        __syncthreads();
        sm[threadIdx.x] += t;
        __syncthreads();
    }
    if (i < N) offs[i] = sm[threadIdx.x] - v;              // exclusive
    if (threadIdx.x == SCAN_BLOCK - 1) bsums[blockIdx.x] = sm[SCAN_BLOCK - 1];
}

// Each block redundantly reduces bsums[0..blockIdx) with one wave (nb tiny).
__global__ void scan_finalize_kernel(int* __restrict__ offs, const int* __restrict__ bsums,
                                     int nb, int N, int E) {
    __shared__ int prefix_sm;
    if (threadIdx.x < 64) {
        int lane = threadIdx.x;
        int acc = 0;
        for (int j = lane; j < nb; j += 64)
            if (j < (int)blockIdx.x) acc += bsums[j];
        #pragma unroll
        for (int m = 1; m < 64; m <<= 1) acc += __shfl_xor(acc, m);
        if (lane == 0) prefix_sm = acc;
    }
    __syncthreads();
    int i = blockIdx.x * SCAN_BLOCK + threadIdx.x;
    if (i < N) offs[i] += prefix_sm;
    if (i == 0) offs[N] = E;
}

// Atomic-free scatter: slot = offs[n] + colprefix[b][n] + lrank[e].
__global__ void scatter_kernel(const int4* __restrict__ edge4, const int* __restrict__ offs,
                               const ushort* __restrict__ part, const ushort* __restrict__ lrank,
                               int* __restrict__ bucket, int E4, int chunk, int N) {
    int i = blockIdx.x * blockDim.x + threadIdx.x;
    if (i >= E4) return;
    int e = i * 4;
    int b = e / chunk;                       // chunk %4==0 -> e..e+3 same b
    const ushort* rel = part + (size_t)b * N;
    int4 idx = edge4[i];
    ushort4 rk = *(const ushort4*)(lrank + e);
    bucket[offs[idx.x] + rel[idx.x] + rk.x] = e + 0;
    bucket[offs[idx.y] + rel[idx.y] + rk.y] = e + 1;
    bucket[offs[idx.z] + rel[idx.z] + rk.z] = e + 2;
    bucket[offs[idx.w] + rel[idx.w] + rk.w] = e + 3;
}

// One wave per node. g = lane>>4 (edge sub-slot), fq = lane&15 (float4 slot).
__global__ __launch_bounds__(256, 8)
void gather_kernel(const int* __restrict__ offs, const int* __restrict__ bucket,
                   const f4vec* __restrict__ w4, f4vec* __restrict__ out4, int N) {
    int n = blockIdx.x * blockDim.y + threadIdx.y;
    if (n >= N) return;
    int lane = threadIdx.x;
    int g  = lane >> 4;
    int fq = lane & 15;
    int s = offs[n], t = offs[n + 1];

    f4vec a0 = {0.f, 0.f, 0.f, 0.f};
    f4vec a1 = {0.f, 0.f, 0.f, 0.f};
    f4vec a2 = {0.f, 0.f, 0.f, 0.f};
    f4vec a3 = {0.f, 0.f, 0.f, 0.f};
    int e = s;
    for (; e + 16 <= t; e += 16) {
        int r0 = bucket[e + g];
        int r1 = bucket[e + 4 + g];
        int r2 = bucket[e + 8 + g];
        int r3 = bucket[e + 12 + g];
        a0 += ntload(w4 + (long long)r0 * 16 + fq);
        a1 += ntload(w4 + (long long)r1 * 16 + fq);
        a2 += ntload(w4 + (long long)r2 * 16 + fq);
        a3 += ntload(w4 + (long long)r3 * 16 + fq);
    }
    if (e + 8 <= t) {
        int r0 = bucket[e + g];
        int r1 = bucket[e + 4 + g];
        a0 += ntload(w4 + (long long)r0 * 16 + fq);
        a1 += ntload(w4 + (long long)r1 * 16 + fq);
        e += 8;
    }
    if (e + g < t)     a2 += ntload(w4 + (long long)bucket[e + g] * 16 + fq);
    if (e + 4 + g < t) a3 += ntload(w4 + (long long)bucket[e + 4 + g] * 16 + fq);
    a0 += a1;
    a2 += a3;
    a0 += a2;
    #pragma unroll
    for (int m = 16; m <= 32; m <<= 1) {
        a0.x += __shfl_xor(a0.x, m);
        a0.y += __shfl_xor(a0.y, m);
        a0.z += __shfl_xor(a0.z, m);
        a0.w += __shfl_xor(a0.w, m);
    }
    if (g == 0) __builtin_nontemporal_store(a0, out4 + (long long)n * 16 + fq);
}

extern "C" void kernel_launch(void* const* d_in, const int* in_sizes, int n_in,
                              void* d_out, int out_size, void* d_ws, size_t ws_size,
                              hipStream_t stream) {
    const int*   edge   = (const int*)d_in[0];     // (2, E): edge[0] = first E entries
    const float* edge_w = (const float*)d_in[1];   // (E, 64) fp32
    float*       out    = (float*)d_out;           // (N, 64) fp32

    int E = in_sizes[0] / 2;
    int N = out_size / NFEAT;
    int nb = (N + SCAN_BLOCK - 1) / SCAN_BLOCK;

    size_t need = ((size_t)(N + 1) + (size_t)nb + (size_t)E) * sizeof(int)
                + (size_t)E * sizeof(ushort)
                + (size_t)HIST_B * (size_t)N * sizeof(ushort) + 64;
    bool ok = (E % 4 == 0) && (N % 2 == 0) && (N <= 2 * NODE_HALF);
    if (ws_size < need || !ok) {
        hipMemsetAsync(d_out, 0, (size_t)out_size * sizeof(float), stream);
        long long n_vec = (long long)E * (NFEAT / 4);
        spmm_scatter_add_kernel<<<(unsigned)((n_vec + 255) / 256), 256, 0, stream>>>(
            edge, (const float4*)edge_w, out, n_vec);
        return;
    }

    int*    offs   = (int*)d_ws;               // N+1
    int*    bsums  = offs + (N + 1);           // nb
    int*    bucket = bsums + nb;               // E
    ushort* lrank  = (ushort*)(bucket + E);    // E  (2.5MB, 4B-aligned)
    ushort* part   = lrank + E;                // HIST_B * N (12.8MB, 4B-aligned)

    int E4 = E / 4;
    int chunk = ((E4 + HIST_B - 1) / HIST_B) * 4;   // edges per hist block, %4==0

    hist_lds_kernel<<<HIST_B, HIST_T, 0, stream>>>(edge, part, lrank, E, chunk, N);
    scan_block_kernel<<<nb, SCAN_BLOCK, 0, stream>>>(part, offs, bsums, N, HIST_B);
    scan_finalize_kernel<<<nb, SCAN_BLOCK, 0, stream>>>(offs, bsums, nb, N, E);
    scatter_kernel<<<(E4 + 255) / 256, 256, 0, stream>>>(
        (const int4*)edge, offs, part, lrank, bucket, E4, chunk, N);

    dim3 gblock(64, 4);
    gather_kernel<<<(N + 3) / 4, gblock, 0, stream>>>(
        offs, bucket, (const f4vec*)edge_w, (f4vec*)out, N);
}